// Round 10
// baseline (743.946 us; speedup 1.0000x reference)
//
#include <hip/hip_runtime.h>
#include <stdint.h>

#define B_   16
#define C_   192
#define TX_  512
#define TY_  2048
#define K_   384       // 2*C
#define SEG_ 32
#define NEG_INF_ (-1e9f)

typedef float f32x4 __attribute__((ext_vector_type(4)));

// Output layout (floats) in d_out:
//   z_slice : [16,192,32]    @ 0         (98304)
//   ids     : [16] (as f32)  @ 98304     (16)
//   attn    : [16,2048,512]  @ 98320     (16777216)
//   m_p_a   : [16,192,2048]  @ 16875536  (6291456)
//   logs_p_a: [16,192,2048]  @ 23166992  (6291456)

// ---------------------------------------------------------------------------
// K0: build B-matrix [b, k, tx] (k<192: s = exp(-2 logs); k>=192: s*m_p) and
//     c_term[b,tx] = sum_c (-0.5 s m^2 - logs)
// ---------------------------------------------------------------------------
__global__ __launch_bounds__(128) void k_prep(const float* __restrict__ mp,
                                              const float* __restrict__ logsp,
                                              float* __restrict__ Bmat,
                                              float* __restrict__ cterm) {
    int b  = blockIdx.y;
    int tx = blockIdx.x * 128 + threadIdx.x;
    const float* mb = mp    + (size_t)b * C_ * TX_ + tx;
    const float* lb = logsp + (size_t)b * C_ * TX_ + tx;
    float* B0 = Bmat + (size_t)b * K_ * TX_ + tx;
    float acc = 0.f;
    for (int c = 0; c < C_; ++c) {
        float lg = lb[(size_t)c * TX_];
        float m  = mb[(size_t)c * TX_];
        float s  = expf(-2.f * lg);
        B0[(size_t)c * TX_]        = s;
        B0[(size_t)(C_ + c) * TX_] = s * m;
        acc += -0.5f * s * m * m - lg;
    }
    cterm[b * TX_ + tx] = acc;
}

// ---------------------------------------------------------------------------
// K1: neg_cent GEMM.  C[b, ty, tx] = sum_k A[b,k,ty]*B[b,k,tx] + cterm[b,tx]
//     A is derived on the fly from z_p: k<192 -> -0.5*z^2 ; k>=192 -> z.
//     128x128 tile, 256 threads, 8x8 accumulators/thread, K-block 16.
// ---------------------------------------------------------------------------
__global__ __launch_bounds__(256) void k_gemm(const float* __restrict__ zp,
                                              const float* __restrict__ Bmat,
                                              const float* __restrict__ cterm,
                                              float* __restrict__ ncout) {
    __shared__ float As[16][128];
    __shared__ float Bs[16][128];
    int b  = blockIdx.z;
    int m0 = blockIdx.y * 128;   // ty
    int n0 = blockIdx.x * 128;   // tx
    int tid = threadIdx.x;
    int tm = tid >> 4;           // 0..15
    int tn = tid & 15;           // 0..15
    const float* zpb = zp   + (size_t)b * C_ * TY_;
    const float* Bb  = Bmat + (size_t)b * K_ * TX_;

    float acc[8][8];
#pragma unroll
    for (int i = 0; i < 8; ++i)
#pragma unroll
        for (int j = 0; j < 8; ++j) acc[i][j] = 0.f;

    int lrow = tid >> 5;           // 0..7
    int lcol = (tid & 31) << 2;    // 0..124

    for (int k0 = 0; k0 < K_; k0 += 16) {
        int ksrc = (k0 < C_) ? k0 : (k0 - C_);
        const float* Ab = zpb + (size_t)(ksrc + lrow) * TY_ + m0 + lcol;
        float4 z0 = *(const float4*)Ab;
        float4 z1 = *(const float4*)(Ab + (size_t)8 * TY_);
        if (k0 < C_) {
            z0.x = -0.5f * z0.x * z0.x; z0.y = -0.5f * z0.y * z0.y;
            z0.z = -0.5f * z0.z * z0.z; z0.w = -0.5f * z0.w * z0.w;
            z1.x = -0.5f * z1.x * z1.x; z1.y = -0.5f * z1.y * z1.y;
            z1.z = -0.5f * z1.z * z1.z; z1.w = -0.5f * z1.w * z1.w;
        }
        const float* Bp = Bb + (size_t)(k0 + lrow) * TX_ + n0 + lcol;
        float4 w0 = *(const float4*)Bp;
        float4 w1 = *(const float4*)(Bp + (size_t)8 * TX_);

        __syncthreads();   // prior iteration's reads done before overwrite
        *(float4*)&As[lrow][lcol]     = z0;
        *(float4*)&As[lrow + 8][lcol] = z1;
        *(float4*)&Bs[lrow][lcol]     = w0;
        *(float4*)&Bs[lrow + 8][lcol] = w1;
        __syncthreads();

#pragma unroll
        for (int kk = 0; kk < 16; ++kk) {
            float4 a0 = *(const float4*)&As[kk][tm * 8];
            float4 a1 = *(const float4*)&As[kk][tm * 8 + 4];
            float4 b0 = *(const float4*)&Bs[kk][tn * 8];
            float4 b1 = *(const float4*)&Bs[kk][tn * 8 + 4];
            float a[8]  = {a0.x, a0.y, a0.z, a0.w, a1.x, a1.y, a1.z, a1.w};
            float bb[8] = {b0.x, b0.y, b0.z, b0.w, b1.x, b1.y, b1.z, b1.w};
#pragma unroll
            for (int i = 0; i < 8; ++i)
#pragma unroll
                for (int j = 0; j < 8; ++j)
                    acc[i][j] = fmaf(a[i], bb[j], acc[i][j]);
        }
    }

    float cadd[8];
#pragma unroll
    for (int j = 0; j < 8; ++j) cadd[j] = cterm[b * TX_ + n0 + tn * 8 + j];

#pragma unroll
    for (int i = 0; i < 8; ++i) {
        int row = m0 + tm * 8 + i;
        float* orow = ncout + ((size_t)b * TY_ + row) * TX_ + n0 + tn * 8;
        float4 o0, o1;
        o0.x = acc[i][0] + cadd[0]; o0.y = acc[i][1] + cadd[1];
        o0.z = acc[i][2] + cadd[2]; o0.w = acc[i][3] + cadd[3];
        o1.x = acc[i][4] + cadd[4]; o1.y = acc[i][5] + cadd[5];
        o1.z = acc[i][6] + cadd[6]; o1.w = acc[i][7] + cadd[7];
        *(float4*)orow       = o0;
        *(float4*)(orow + 4) = o1;
    }
}

// ---------------------------------------------------------------------------
// K2: fused DP forward + backward. Barrier-phased + fully asm row (r10).
//
// History (k_dp µs): r0 423 / r6 424 / r7 385 / r8 416 / r9 359. r9 proved
// (asm-guaranteed batched ds_reads, absmax 0.0) that load latency is NOT
// the wall: ~420 cyc/row remained for ~45 VALU ops -> IPC ~0.1. Cause: the
// compiler's row schedule routes every compare through the single vcc with
// the consumer 1 instr behind, on an in-order SIMD with ONE resident wave
// -> every dep is a full stall. r10: hand-scheduled 39-instr asm per row.
// Four interleaved streams (cmp / max / add / bit-or); every consumer >=3
// instrs (>=6 cyc) behind its producer; vcc reused at distance 3-4; temps
// rotate through 3 regs; bit consts are VOP3 inline (64..1) + one VGPR for
// 128. Issue floor ~80 cyc/row. DPP left stays the proven builtin (outside
// asm, feeds it as input). Semantics bit-identical to the absmax-0.0
// lineage: v[k]' = max(v[k], v[k-1]) + rc[k]; bit_k = (v[k-1] > v[k]).
//
// Structure (unchanged from r9): block = 9 waves; wave 0 consumer, waves
// 1..8 producers 4 rows each/phase. LDS = 2 x 64KB halves (32 rows x 2KB);
// phase sg: producers fill half (sg+1)&1, consumer drains half sg&1 via
// asm-batched 16x ds_read_b128 + lgkmcnt(0) per 8-row group; one barrier
// per phase. Dirn dwords -> gdirs (= m_p_a region, overwritten later by
// k_proj), drained at the phase barrier. After forward, all waves copy
// gdirs into LDS (original layout); proven backward walk unchanged. Rows
// >= t_y processed as harmless garbage (bits never consulted).
// ---------------------------------------------------------------------------
#if __has_builtin(__builtin_amdgcn_update_dpp)
// wave_shr:1 (dpp_ctrl 0x138): lane L <- lane L-1; lane 0 <- old (=NEG_INF).
#define LEFT_OF(v7)                                                          \
    __int_as_float(__builtin_amdgcn_update_dpp(                              \
        __float_as_int(NEG_INF_), __float_as_int(v7), 0x138, 0xF, 0xF, false))
#else
#define LEFT_OF(v7)                                                         \
    ({ float _l = __shfl_up((v7), 1); if (lane == 0) _l = NEG_INF_; _l; })
#endif

// One 8-row group: 16x ds_read_b128 + wait, atomically in one asm block.
#define DS_READ_GROUP(qq, addr)                                              \
    asm volatile(                                                            \
        "ds_read_b128 %0,  %16 offset:0\n\t"                                 \
        "ds_read_b128 %1,  %16 offset:1024\n\t"                              \
        "ds_read_b128 %2,  %16 offset:2048\n\t"                              \
        "ds_read_b128 %3,  %16 offset:3072\n\t"                              \
        "ds_read_b128 %4,  %16 offset:4096\n\t"                              \
        "ds_read_b128 %5,  %16 offset:5120\n\t"                              \
        "ds_read_b128 %6,  %16 offset:6144\n\t"                              \
        "ds_read_b128 %7,  %16 offset:7168\n\t"                              \
        "ds_read_b128 %8,  %16 offset:8192\n\t"                              \
        "ds_read_b128 %9,  %16 offset:9216\n\t"                              \
        "ds_read_b128 %10, %16 offset:10240\n\t"                             \
        "ds_read_b128 %11, %16 offset:11264\n\t"                             \
        "ds_read_b128 %12, %16 offset:12288\n\t"                             \
        "ds_read_b128 %13, %16 offset:13312\n\t"                             \
        "ds_read_b128 %14, %16 offset:14336\n\t"                             \
        "ds_read_b128 %15, %16 offset:15360\n\t"                             \
        "s_waitcnt lgkmcnt(0)"                                               \
        : "=&v"(qq[0]),  "=&v"(qq[1]),  "=&v"(qq[2]),  "=&v"(qq[3]),         \
          "=&v"(qq[4]),  "=&v"(qq[5]),  "=&v"(qq[6]),  "=&v"(qq[7]),         \
          "=&v"(qq[8]),  "=&v"(qq[9]),  "=&v"(qq[10]), "=&v"(qq[11]),        \
          "=&v"(qq[12]), "=&v"(qq[13]), "=&v"(qq[14]), "=&v"(qq[15])         \
        : "v"(addr)                                                          \
        : "memory")

// One DP row, hand-scheduled. v[k]' = max(v[k],v[k-1]) + rc[k];
// by bit k = (v[k-1] > v[k]) (vs for k=0 is `left`). Old values only:
// each v[k] is overwritten strictly after its last old-value use.
// vcc producer->consumer distance >= 3 instrs; temps ta/tb/tc rotate.
// Operands: %0-%7 = v0..v7 (+v); %8 = by out; %9 = bt; %10-12 = ta,tb,tc;
// inputs: %13 = left, %14-%21 = rc0..rc7, %22 = c128 (VGPR holding 128).
#define DP_ROW(vv, BY, left_, q0, q1, c128_)                                 \
    {                                                                        \
        unsigned bt_; float ta_, tb_, tc_;                                   \
        asm volatile(                                                        \
            "v_cmp_gt_f32 vcc, %6, %7\n\t"                                   \
            "v_max_f32 %10, %7, %6\n\t"                                      \
            "v_max_f32 %11, %6, %5\n\t"                                      \
            "v_cndmask_b32 %8, 0, %22, vcc\n\t"                              \
            "v_cmp_gt_f32 vcc, %5, %6\n\t"                                   \
            "v_add_f32 %7, %10, %21\n\t"                                     \
            "v_max_f32 %12, %5, %4\n\t"                                      \
            "v_cndmask_b32 %9, 0, 64, vcc\n\t"                               \
            "v_cmp_gt_f32 vcc, %4, %5\n\t"                                   \
            "v_add_f32 %6, %11, %20\n\t"                                     \
            "v_or_b32 %8, %8, %9\n\t"                                        \
            "v_max_f32 %10, %4, %3\n\t"                                      \
            "v_cndmask_b32 %9, 0, 32, vcc\n\t"                               \
            "v_cmp_gt_f32 vcc, %3, %4\n\t"                                   \
            "v_add_f32 %5, %12, %19\n\t"                                     \
            "v_or_b32 %8, %8, %9\n\t"                                        \
            "v_max_f32 %11, %3, %2\n\t"                                      \
            "v_cndmask_b32 %9, 0, 16, vcc\n\t"                               \
            "v_cmp_gt_f32 vcc, %2, %3\n\t"                                   \
            "v_add_f32 %4, %10, %18\n\t"                                     \
            "v_or_b32 %8, %8, %9\n\t"                                        \
            "v_max_f32 %12, %2, %1\n\t"                                      \
            "v_cndmask_b32 %9, 0, 8, vcc\n\t"                                \
            "v_cmp_gt_f32 vcc, %1, %2\n\t"                                   \
            "v_add_f32 %3, %11, %17\n\t"                                     \
            "v_or_b32 %8, %8, %9\n\t"                                        \
            "v_max_f32 %10, %1, %0\n\t"                                      \
            "v_cndmask_b32 %9, 0, 4, vcc\n\t"                                \
            "v_cmp_gt_f32 vcc, %0, %1\n\t"                                   \
            "v_add_f32 %2, %12, %16\n\t"                                     \
            "v_or_b32 %8, %8, %9\n\t"                                        \
            "v_max_f32 %11, %0, %13\n\t"                                     \
            "v_cndmask_b32 %9, 0, 2, vcc\n\t"                                \
            "v_cmp_gt_f32 vcc, %13, %0\n\t"                                  \
            "v_add_f32 %1, %10, %15\n\t"                                     \
            "v_or_b32 %8, %8, %9\n\t"                                        \
            "v_cndmask_b32 %9, 0, 1, vcc\n\t"                                \
            "v_add_f32 %0, %11, %14\n\t"                                     \
            "v_or_b32 %8, %8, %9"                                            \
            : "+v"(vv[0]), "+v"(vv[1]), "+v"(vv[2]), "+v"(vv[3]),            \
              "+v"(vv[4]), "+v"(vv[5]), "+v"(vv[6]), "+v"(vv[7]),            \
              "=&v"(BY), "=&v"(bt_), "=&v"(ta_), "=&v"(tb_), "=&v"(tc_)      \
            : "v"(left_),                                                    \
              "v"(q0[0]), "v"(q0[1]), "v"(q0[2]), "v"(q0[3]),                \
              "v"(q1[0]), "v"(q1[1]), "v"(q1[2]), "v"(q1[3]),                \
              "v"(c128_)                                                     \
            : "vcc");                                                        \
    }

__global__ __launch_bounds__(576, 1) void k_dp(const float* __restrict__ nc,
                                               const int* __restrict__ xl,
                                               const int* __restrict__ yl,
                                               int* __restrict__ path,
                                               int* __restrict__ gdirs) {
    extern __shared__ unsigned char sdirs[];   // 131072 B: 2 x 64KB halves
    float* stage = (float*)sdirs;              // half h at float offset h*16384
    int b    = blockIdx.x;
    int tid  = threadIdx.x;
    int wid  = tid >> 6;                       // 0 = consumer, 1..8 producers
    int lane = tid & 63;
    int t_x  = xl[b];
    int t_y  = yl[b]; if (t_y > TY_) t_y = TY_;
    const float* ncb = nc + (size_t)b * TY_ * TX_;
    int* gd32 = gdirs + b * (TY_ * 64 / 4);    // 32768 dwords per block

    int nsg = (t_y + 31) >> 5;                 // 32-row phases

    // ---- prologue: producers fill half 0 with rows 0..31 (4 rows each) ----
    if (wid > 0) {
        int w = wid - 1;
        float* lb = stage + (4 * w) * 512 + lane * 4;
        const float* gp = ncb + (size_t)(4 * w) * TX_ + lane * 8;
#pragma unroll
        for (int r = 0; r < 4; ++r) {
            float4 a = *(const float4*)(gp + (size_t)r * TX_);
            float4 c = *(const float4*)(gp + (size_t)r * TX_ + 4);
            *(float4*)(lb + r * 512)       = a;
            *(float4*)(lb + r * 512 + 256) = c;
        }
    }

    float v[8];
    {
        int col0 = lane * 8;
#pragma unroll
        for (int k = 0; k < 8; ++k) v[k] = (col0 + k == 0) ? 0.f : NEG_INF_;
    }
    unsigned c128 = 128u;   // bit7 constant (not VOP3-inline)

    for (int sg = 0; sg < nsg; ++sg) {
        __syncthreads();   // half sg&1 filled; half (sg+1)&1 free

        if (wid > 0) {
            // ---- producers: fill half (sg+1)&1 with rows of phase sg+1 ----
            int sgn = sg + 1;
            if (sgn < nsg) {
                int w = wid - 1;
                int row0 = sgn * 32 + 4 * w;   // < nsg*32 <= 2048, in-bounds
                float* lb = stage + ((sgn & 1) * 16384) + (4 * w) * 512 + lane * 4;
                const float* gp = ncb + (size_t)row0 * TX_ + lane * 8;
#pragma unroll
                for (int r = 0; r < 4; ++r) {
                    float4 a = *(const float4*)(gp + (size_t)r * TX_);
                    float4 c = *(const float4*)(gp + (size_t)r * TX_ + 4);
                    *(float4*)(lb + r * 512)       = a;
                    *(float4*)(lb + r * 512 + 256) = c;
                }
            }
        } else {
            // ---- consumer: 4 asm-batched groups of 8 asm-scheduled rows ----
            unsigned hbase = (unsigned)((sg & 1) * 65536 + lane * 16);
            f32x4 qq[16];
#pragma unroll
            for (int g = 0; g < 4; ++g) {
                unsigned addr = hbase + (unsigned)(g * 16384);
                DS_READ_GROUP(qq, addr);
                unsigned dw0 = 0u, dw1 = 0u;
#pragma unroll
                for (int r = 0; r < 8; ++r) {
                    float left = LEFT_OF(v[7]);
                    unsigned by;
                    DP_ROW(v, by, left, qq[2 * r], qq[2 * r + 1], c128);
                    if (r < 4) dw0 |= by << (8 * r);
                    else       dw1 |= by << (8 * (r - 4));
                }
                int gidx = sg * 4 + g;
                gd32[(2 * gidx)     * 64 + lane] = (int)dw0;   // fire-and-forget;
                gd32[(2 * gidx + 1) * 64 + lane] = (int)dw1;   // drains at barrier
            }
        }
    }

    __syncthreads();   // forward done everywhere

    // reload dirn bits into LDS (both halves free now; layout identical to
    // the original sdirs32 layout the backward walk expects)
    {
        const float4* g4 = (const float4*)gd32;
        float4* s4 = (float4*)sdirs;
        for (int i = tid; i < TY_ * 16 / 4; i += 576) s4[i] = g4[i];
    }
    __syncthreads();

    int* pb = path + b * TY_;
    for (int j = t_y + tid; j < TY_; j += 576) pb[j] = -1;

    if (tid == 0) {
        int idx = t_x - 1;
        int j   = t_y - 1;
        while (j >= 0) {
            int n  = (j + 1 < 8) ? (j + 1) : 8;
            int bs = (idx - 7) >> 3; if (bs < 0) bs = 0;
            int b2 = bs + 1;         if (b2 > 63) b2 = 63;
            unsigned lo[8], hi[8];
#pragma unroll
            for (int r = 0; r < 8; ++r) {
                if (r < n) {
                    int jr = j - r;
                    int rb = (jr >> 2) * 256 + (jr & 3);
                    lo[r] = sdirs[rb + bs * 4];
                    hi[r] = sdirs[rb + b2 * 4];
                }
            }
#pragma unroll
            for (int r = 0; r < 8; ++r) {
                if (r < n) {
                    pb[j - r] = idx;
                    int Bi = idx >> 3;
                    unsigned byte = (Bi == bs) ? lo[r] : hi[r];
                    idx -= (int)((byte >> (idx & 7)) & 1u);
                }
            }
            j -= n;
        }
    }
}

// ---------------------------------------------------------------------------
// K4a: attn one-hot write (overwrites the neg_cent scratch region).
// ---------------------------------------------------------------------------
__global__ __launch_bounds__(256) void k_attn(const int* __restrict__ path,
                                              float* __restrict__ attn) {
    int i   = blockIdx.x * 256 + threadIdx.x;   // over B*TY*TX/4
    int tx0 = (i & 127) << 2;                   // TX/4 = 128
    int bty = i >> 7;                           // b*TY + ty
    int p   = path[bty];
    float4 o;
    o.x = (p == tx0)     ? 1.f : 0.f;
    o.y = (p == tx0 + 1) ? 1.f : 0.f;
    o.z = (p == tx0 + 2) ? 1.f : 0.f;
    o.w = (p == tx0 + 3) ? 1.f : 0.f;
    ((float4*)attn)[i] = o;
}

// ---------------------------------------------------------------------------
// K4b: m_p_a / logs_p_a gather: out[b,c,ty] = (path[ty]>=0) ? in[b,c,path] : 0
// ---------------------------------------------------------------------------
__global__ __launch_bounds__(256) void k_proj(const int* __restrict__ path,
                                              const float* __restrict__ mp,
                                              const float* __restrict__ logsp,
                                              float* __restrict__ mpa,
                                              float* __restrict__ logsa) {
    int i   = blockIdx.x * 256 + threadIdx.x;   // over B*C*TY/4
    int ty0 = (i & 511) << 2;                   // TY/4 = 512
    int bc  = i >> 9;                           // b*C + c
    int b   = bc / C_;
    const int4 p4 = *(const int4*)(path + b * TY_ + ty0);
    const float* mrow = mp    + (size_t)bc * TX_;
    const float* lrow = logsp + (size_t)bc * TX_;
    float4 mo, lo;
    mo.x = (p4.x >= 0) ? mrow[p4.x] : 0.f;  lo.x = (p4.x >= 0) ? lrow[p4.x] : 0.f;
    mo.y = (p4.y >= 0) ? mrow[p4.y] : 0.f;  lo.y = (p4.y >= 0) ? lrow[p4.y] : 0.f;
    mo.z = (p4.z >= 0) ? mrow[p4.z] : 0.f;  lo.z = (p4.z >= 0) ? lrow[p4.z] : 0.f;
    mo.w = (p4.w >= 0) ? mrow[p4.w] : 0.f;  lo.w = (p4.w >= 0) ? lrow[p4.w] : 0.f;
    ((float4*)mpa)[i]   = mo;
    ((float4*)logsa)[i] = lo;
}

// ---------------------------------------------------------------------------
// K4c: random segment slice of z + ids output (replicates ref f32 math).
// ---------------------------------------------------------------------------
__global__ __launch_bounds__(256) void k_slice(const float* __restrict__ z,
                                               const int* __restrict__ yl,
                                               const float* __restrict__ ru,
                                               float* __restrict__ zs,
                                               float* __restrict__ oid) {
    int b = blockIdx.x;
    int safe = yl[b]; if (safe > TY_) safe = TY_;
    int idsmax = safe - SEG_; if (idsmax < 0) idsmax = 0;
    int ids = (int)(ru[b] * ((float)idsmax + 1e-8f));
    int lim = safe - ids;
    for (int t = threadIdx.x; t < C_ * SEG_; t += 256) {
        int c = t >> 5, k = t & 31;
        zs[b * C_ * SEG_ + t] =
            (k < lim) ? z[((size_t)b * C_ + c) * TY_ + ids + k] : 0.f;
    }
    if (threadIdx.x == 0) oid[b] = (float)ids;
}

// ---------------------------------------------------------------------------
extern "C" void kernel_launch(void* const* d_in, const int* in_sizes, int n_in,
                              void* d_out, int out_size, void* d_ws, size_t ws_size,
                              hipStream_t stream) {
    const float* z     = (const float*)d_in[0];
    const float* zp    = (const float*)d_in[1];
    const float* mp    = (const float*)d_in[2];
    const float* logsp = (const float*)d_in[3];
    const int*   xl    = (const int*)d_in[4];
    const int*   yl    = (const int*)d_in[5];
    const float* ru    = (const float*)d_in[6];

    float* out     = (float*)d_out;
    float* o_zs    = out;                  // 98304
    float* o_ids   = out + 98304;          // 16
    float* o_attn  = out + 98320;          // 16777216 (also neg_cent scratch)
    float* o_mpa   = out + 16875536;       // 6291456
    float* o_logsa = out + 23166992;       // 6291456

    float* Bmat  = (float*)d_ws;                        // 3,145,728 f
    float* cterm = Bmat + (size_t)B_ * K_ * TX_;        // 8192 f
    int*   path  = (int*)(cterm + B_ * TX_);            // 32768 i32
    int*   gdirs = (int*)o_mpa;   // 2 MB dirn scratch; k_proj overwrites later

    // allow 128 KiB dynamic LDS for the fused DP kernel (host-side, not a
    // stream op — safe under graph capture; idempotent, called every launch)
    hipFuncSetAttribute((const void*)k_dp,
                        hipFuncAttributeMaxDynamicSharedMemorySize,
                        TY_ * 64);

    hipLaunchKernelGGL(k_prep, dim3(TX_ / 128, B_), dim3(128), 0, stream,
                       mp, logsp, Bmat, cterm);
    hipLaunchKernelGGL(k_gemm, dim3(TX_ / 128, TY_ / 128, B_), dim3(256), 0, stream,
                       zp, Bmat, cterm, o_attn);
    hipLaunchKernelGGL(k_dp, dim3(B_), dim3(576), TY_ * 64, stream,
                       o_attn, xl, yl, path, gdirs);
    hipLaunchKernelGGL(k_attn, dim3(B_ * TY_ * TX_ / 4 / 256), dim3(256), 0, stream,
                       path, o_attn);
    hipLaunchKernelGGL(k_proj, dim3(B_ * C_ * TY_ / 4 / 256), dim3(256), 0, stream,
                       path, mp, logsp, o_mpa, o_logsa);
    hipLaunchKernelGGL(k_slice, dim3(B_), dim3(256), 0, stream,
                       z, yl, ru, o_zs, o_ids);
}

// Round 11
// 740.119 us; speedup vs baseline: 1.0052x; 1.0052x over previous
//
#include <hip/hip_runtime.h>
#include <stdint.h>

#define B_   16
#define C_   192
#define TX_  512
#define TY_  2048
#define K_   384       // 2*C
#define SEG_ 32
#define NEG_INF_ (-1e9f)

typedef float f32x4 __attribute__((ext_vector_type(4)));

// Output layout (floats) in d_out:
//   z_slice : [16,192,32]    @ 0         (98304)
//   ids     : [16] (as f32)  @ 98304     (16)
//   attn    : [16,2048,512]  @ 98320     (16777216)
//   m_p_a   : [16,192,2048]  @ 16875536  (6291456)
//   logs_p_a: [16,192,2048]  @ 23166992  (6291456)

// ---------------------------------------------------------------------------
// K0: build B-matrix [b, k, tx] (k<192: s = exp(-2 logs); k>=192: s*m_p) and
//     c_term[b,tx] = sum_c (-0.5 s m^2 - logs)
// ---------------------------------------------------------------------------
__global__ __launch_bounds__(128) void k_prep(const float* __restrict__ mp,
                                              const float* __restrict__ logsp,
                                              float* __restrict__ Bmat,
                                              float* __restrict__ cterm) {
    int b  = blockIdx.y;
    int tx = blockIdx.x * 128 + threadIdx.x;
    const float* mb = mp    + (size_t)b * C_ * TX_ + tx;
    const float* lb = logsp + (size_t)b * C_ * TX_ + tx;
    float* B0 = Bmat + (size_t)b * K_ * TX_ + tx;
    float acc = 0.f;
    for (int c = 0; c < C_; ++c) {
        float lg = lb[(size_t)c * TX_];
        float m  = mb[(size_t)c * TX_];
        float s  = expf(-2.f * lg);
        B0[(size_t)c * TX_]        = s;
        B0[(size_t)(C_ + c) * TX_] = s * m;
        acc += -0.5f * s * m * m - lg;
    }
    cterm[b * TX_ + tx] = acc;
}

// ---------------------------------------------------------------------------
// K1: neg_cent GEMM.  C[b, ty, tx] = sum_k A[b,k,ty]*B[b,k,tx] + cterm[b,tx]
//     A is derived on the fly from z_p: k<192 -> -0.5*z^2 ; k>=192 -> z.
//     128x128 tile, 256 threads, 8x8 accumulators/thread, K-block 16.
// ---------------------------------------------------------------------------
__global__ __launch_bounds__(256) void k_gemm(const float* __restrict__ zp,
                                              const float* __restrict__ Bmat,
                                              const float* __restrict__ cterm,
                                              float* __restrict__ ncout) {
    __shared__ float As[16][128];
    __shared__ float Bs[16][128];
    int b  = blockIdx.z;
    int m0 = blockIdx.y * 128;   // ty
    int n0 = blockIdx.x * 128;   // tx
    int tid = threadIdx.x;
    int tm = tid >> 4;           // 0..15
    int tn = tid & 15;           // 0..15
    const float* zpb = zp   + (size_t)b * C_ * TY_;
    const float* Bb  = Bmat + (size_t)b * K_ * TX_;

    float acc[8][8];
#pragma unroll
    for (int i = 0; i < 8; ++i)
#pragma unroll
        for (int j = 0; j < 8; ++j) acc[i][j] = 0.f;

    int lrow = tid >> 5;           // 0..7
    int lcol = (tid & 31) << 2;    // 0..124

    for (int k0 = 0; k0 < K_; k0 += 16) {
        int ksrc = (k0 < C_) ? k0 : (k0 - C_);
        const float* Ab = zpb + (size_t)(ksrc + lrow) * TY_ + m0 + lcol;
        float4 z0 = *(const float4*)Ab;
        float4 z1 = *(const float4*)(Ab + (size_t)8 * TY_);
        if (k0 < C_) {
            z0.x = -0.5f * z0.x * z0.x; z0.y = -0.5f * z0.y * z0.y;
            z0.z = -0.5f * z0.z * z0.z; z0.w = -0.5f * z0.w * z0.w;
            z1.x = -0.5f * z1.x * z1.x; z1.y = -0.5f * z1.y * z1.y;
            z1.z = -0.5f * z1.z * z1.z; z1.w = -0.5f * z1.w * z1.w;
        }
        const float* Bp = Bb + (size_t)(k0 + lrow) * TX_ + n0 + lcol;
        float4 w0 = *(const float4*)Bp;
        float4 w1 = *(const float4*)(Bp + (size_t)8 * TX_);

        __syncthreads();   // prior iteration's reads done before overwrite
        *(float4*)&As[lrow][lcol]     = z0;
        *(float4*)&As[lrow + 8][lcol] = z1;
        *(float4*)&Bs[lrow][lcol]     = w0;
        *(float4*)&Bs[lrow + 8][lcol] = w1;
        __syncthreads();

#pragma unroll
        for (int kk = 0; kk < 16; ++kk) {
            float4 a0 = *(const float4*)&As[kk][tm * 8];
            float4 a1 = *(const float4*)&As[kk][tm * 8 + 4];
            float4 b0 = *(const float4*)&Bs[kk][tn * 8];
            float4 b1 = *(const float4*)&Bs[kk][tn * 8 + 4];
            float a[8]  = {a0.x, a0.y, a0.z, a0.w, a1.x, a1.y, a1.z, a1.w};
            float bb[8] = {b0.x, b0.y, b0.z, b0.w, b1.x, b1.y, b1.z, b1.w};
#pragma unroll
            for (int i = 0; i < 8; ++i)
#pragma unroll
                for (int j = 0; j < 8; ++j)
                    acc[i][j] = fmaf(a[i], bb[j], acc[i][j]);
        }
    }

    float cadd[8];
#pragma unroll
    for (int j = 0; j < 8; ++j) cadd[j] = cterm[b * TX_ + n0 + tn * 8 + j];

#pragma unroll
    for (int i = 0; i < 8; ++i) {
        int row = m0 + tm * 8 + i;
        float* orow = ncout + ((size_t)b * TY_ + row) * TX_ + n0 + tn * 8;
        float4 o0, o1;
        o0.x = acc[i][0] + cadd[0]; o0.y = acc[i][1] + cadd[1];
        o0.z = acc[i][2] + cadd[2]; o0.w = acc[i][3] + cadd[3];
        o1.x = acc[i][4] + cadd[4]; o1.y = acc[i][5] + cadd[5];
        o1.z = acc[i][6] + cadd[6]; o1.w = acc[i][7] + cadd[7];
        *(float4*)orow       = o0;
        *(float4*)(orow + 4) = o1;
    }
}

// ---------------------------------------------------------------------------
// K2: fused DP forward + backward. Barrier-phased; asm producer + asm reads.
//
// History (k_dp µs): r0 423 / r6 424 / r7 385 / r8 416 / r9 359 / r10 382.
// r9 (asm-batched consumer reads) and r10 (hand-scheduled asm row, issue
// floor ~80cyc/row) both failed to move the needle -> the CONSUMER is not
// the critical path (~5K cyc/phase modeled vs 13.4K measured). Remaining
// suspect with the right magnitude: the PRODUCER chain. Producer C code
// loads 4 rows as {load,load,vmcnt,write,write} per row (compiler sinks
// loads to use) = ~4 serial memory latencies (~1-1.5K each under 128-wave
// demand) per phase, plus the consumer's pre-barrier vmcnt(0) drain of its
// 8 dirn stores. r11: (a) producer staging in ONE asm block — 8x
// global_load_dwordx4 (sgpr base + voffset), s_waitcnt vmcnt(0), 8x
// ds_write_b128 — guaranteed batch issue, ONE latency per phase. Safe by
// construction: the wait is inside the block, no deferred defs escape
// (unlike r1's hazard). (b) consumer's dirn dwords buffered in named regs,
// stored right AFTER the next barrier (a whole phase to retire before the
// following drain). (c) consumer row reverts to r9's compiler-scheduled
// form (fastest measured; r10's asm row was slower).
//
// Structure: block = 9 waves; wave 0 consumer, waves 1..8 producers 4 rows
// each/phase. LDS = 2 x 64KB halves (32 rows x 2KB); phase sg: producers
// fill half (sg+1)&1, consumer drains half sg&1 via asm-batched 16x
// ds_read_b128 + lgkmcnt(0) per 8-row group; one barrier per phase.
// Dirn dwords -> gdirs (= m_p_a region, overwritten later by k_proj).
// After forward, all waves copy gdirs into LDS (original layout); proven
// backward walk unchanged. Rows >= t_y processed as harmless garbage
// (their dirn bits are never consulted).
// ---------------------------------------------------------------------------
#if __has_builtin(__builtin_amdgcn_update_dpp)
// wave_shr:1 (dpp_ctrl 0x138): lane L <- lane L-1; lane 0 <- old (=NEG_INF).
#define LEFT_OF(v7)                                                          \
    __int_as_float(__builtin_amdgcn_update_dpp(                              \
        __float_as_int(NEG_INF_), __float_as_int(v7), 0x138, 0xF, 0xF, false))
#else
#define LEFT_OF(v7)                                                         \
    ({ float _l = __shfl_up((v7), 1); if (lane == 0) _l = NEG_INF_; _l; })
#endif

// One 8-row group: 16x ds_read_b128 + wait, atomically in one asm block.
#define DS_READ_GROUP(qq, addr)                                              \
    asm volatile(                                                            \
        "ds_read_b128 %0,  %16 offset:0\n\t"                                 \
        "ds_read_b128 %1,  %16 offset:1024\n\t"                              \
        "ds_read_b128 %2,  %16 offset:2048\n\t"                              \
        "ds_read_b128 %3,  %16 offset:3072\n\t"                              \
        "ds_read_b128 %4,  %16 offset:4096\n\t"                              \
        "ds_read_b128 %5,  %16 offset:5120\n\t"                              \
        "ds_read_b128 %6,  %16 offset:6144\n\t"                              \
        "ds_read_b128 %7,  %16 offset:7168\n\t"                              \
        "ds_read_b128 %8,  %16 offset:8192\n\t"                              \
        "ds_read_b128 %9,  %16 offset:9216\n\t"                              \
        "ds_read_b128 %10, %16 offset:10240\n\t"                             \
        "ds_read_b128 %11, %16 offset:11264\n\t"                             \
        "ds_read_b128 %12, %16 offset:12288\n\t"                             \
        "ds_read_b128 %13, %16 offset:13312\n\t"                             \
        "ds_read_b128 %14, %16 offset:14336\n\t"                             \
        "ds_read_b128 %15, %16 offset:15360\n\t"                             \
        "s_waitcnt lgkmcnt(0)"                                               \
        : "=&v"(qq[0]),  "=&v"(qq[1]),  "=&v"(qq[2]),  "=&v"(qq[3]),         \
          "=&v"(qq[4]),  "=&v"(qq[5]),  "=&v"(qq[6]),  "=&v"(qq[7]),         \
          "=&v"(qq[8]),  "=&v"(qq[9]),  "=&v"(qq[10]), "=&v"(qq[11]),        \
          "=&v"(qq[12]), "=&v"(qq[13]), "=&v"(qq[14]), "=&v"(qq[15])         \
        : "v"(addr)                                                          \
        : "memory")

// Producer: stage 4 rows (8KB) global->LDS in ONE asm block.
// voA = byte offset of row0 (+lane*32); rows 0,1 via imm {0,16,2048,2064};
// voB = voA+4096 covers rows 2,3. Wait INSIDE the block, then 8 ds_writes.
#define STAGE_GROUP(voA_, sb_, laddr_)                                       \
    {                                                                        \
        f32x4 t0_, t1_, t2_, t3_, t4_, t5_, t6_, t7_;                        \
        asm volatile(                                                        \
            "global_load_dwordx4 %0, %8, %10 offset:0\n\t"                   \
            "global_load_dwordx4 %1, %8, %10 offset:16\n\t"                  \
            "global_load_dwordx4 %2, %8, %10 offset:2048\n\t"                \
            "global_load_dwordx4 %3, %8, %10 offset:2064\n\t"                \
            "global_load_dwordx4 %4, %9, %10 offset:0\n\t"                   \
            "global_load_dwordx4 %5, %9, %10 offset:16\n\t"                  \
            "global_load_dwordx4 %6, %9, %10 offset:2048\n\t"                \
            "global_load_dwordx4 %7, %9, %10 offset:2064\n\t"                \
            "s_waitcnt vmcnt(0)\n\t"                                         \
            "ds_write_b128 %11, %0 offset:0\n\t"                             \
            "ds_write_b128 %11, %1 offset:1024\n\t"                          \
            "ds_write_b128 %11, %2 offset:2048\n\t"                          \
            "ds_write_b128 %11, %3 offset:3072\n\t"                          \
            "ds_write_b128 %11, %4 offset:4096\n\t"                          \
            "ds_write_b128 %11, %5 offset:5120\n\t"                          \
            "ds_write_b128 %11, %6 offset:6144\n\t"                          \
            "ds_write_b128 %11, %7 offset:7168"                              \
            : "=&v"(t0_), "=&v"(t1_), "=&v"(t2_), "=&v"(t3_),                \
              "=&v"(t4_), "=&v"(t5_), "=&v"(t6_), "=&v"(t7_)                 \
            : "v"(voA_), "v"((unsigned)((voA_) + 4096u)), "s"(sb_),          \
              "v"(laddr_)                                                    \
            : "memory");                                                     \
    }

__global__ __launch_bounds__(576, 1) void k_dp(const float* __restrict__ nc,
                                               const int* __restrict__ xl,
                                               const int* __restrict__ yl,
                                               int* __restrict__ path,
                                               int* __restrict__ gdirs) {
    extern __shared__ unsigned char sdirs[];   // 131072 B: 2 x 64KB halves
    float* stage = (float*)sdirs;              // half h at float offset h*16384
    int b    = blockIdx.x;
    int tid  = threadIdx.x;
    int wid  = tid >> 6;                       // 0 = consumer, 1..8 producers
    int lane = tid & 63;
    int t_x  = xl[b];
    int t_y  = yl[b]; if (t_y > TY_) t_y = TY_;
    const float* ncb = nc + (size_t)b * TY_ * TX_;
    int* gd32 = gdirs + b * (TY_ * 64 / 4);    // 32768 dwords per block

    int nsg = (t_y + 31) >> 5;                 // 32-row phases

    // ---- prologue: producers fill half 0 with rows 0..31 (4 rows each) ----
    if (wid > 0) {
        int w = wid - 1;
        unsigned voA = (unsigned)((4 * w) * 2048 + lane * 32);
        unsigned la  = (unsigned)(w * 8192 + lane * 16);
        STAGE_GROUP(voA, ncb, la);
    }

    float v[8];
    {
        int col0 = lane * 8;
#pragma unroll
        for (int k = 0; k < 8; ++k) v[k] = (col0 + k == 0) ? 0.f : NEG_INF_;
    }
    unsigned pd[8];   // previous phase's dirn dwords (indices compile-time)

    for (int sg = 0; sg < nsg; ++sg) {
        __syncthreads();   // half sg&1 filled; half (sg+1)&1 free

        if (wid > 0) {
            // ---- producers: fill half (sg+1)&1 with rows of phase sg+1 ----
            int sgn = sg + 1;
            if (sgn < nsg) {
                int w = wid - 1;
                int row0 = sgn * 32 + 4 * w;   // < nsg*32 <= 2048, in-bounds
                unsigned voA = (unsigned)(row0 * 2048 + lane * 32);
                unsigned la  = (unsigned)(((sgn & 1) * 65536) + w * 8192 + lane * 16);
                STAGE_GROUP(voA, ncb, la);
            }
        } else {
            // deferred dirn stores for phase sg-1: a whole phase to retire
            if (sg > 0) {
                int* gp0 = gd32 + (sg - 1) * 512 + lane;
#pragma unroll
                for (int i = 0; i < 8; ++i) gp0[i * 64] = (int)pd[i];
            }
            // ---- consumer: 4 asm-batched groups of 8 rows ----
            unsigned hbase = (unsigned)((sg & 1) * 65536 + lane * 16);
            f32x4 qq[16];
#pragma unroll
            for (int g = 0; g < 4; ++g) {
                unsigned addr = hbase + (unsigned)(g * 16384);
                DS_READ_GROUP(qq, addr);
                unsigned dw0 = 0u, dw1 = 0u;
#pragma unroll
                for (int r = 0; r < 8; ++r) {
                    float rc[8] = {qq[2 * r][0],     qq[2 * r][1],
                                   qq[2 * r][2],     qq[2 * r][3],
                                   qq[2 * r + 1][0], qq[2 * r + 1][1],
                                   qq[2 * r + 1][2], qq[2 * r + 1][3]};
                    float left = LEFT_OF(v[7]);
                    unsigned by = 0u;
#pragma unroll
                    for (int k = 7; k >= 0; --k) {
                        float vs = (k == 0) ? left : v[k - 1];
                        if (vs > v[k]) by |= (1u << k);
                        v[k] = fmaxf(v[k], vs) + rc[k];
                    }
                    if (r < 4) dw0 |= by << (8 * r);
                    else       dw1 |= by << (8 * (r - 4));
                }
                pd[2 * g]     = dw0;
                pd[2 * g + 1] = dw1;
            }
        }
    }
    // last phase's dirn dwords
    if (wid == 0) {
        int* gp0 = gd32 + (nsg - 1) * 512 + lane;
#pragma unroll
        for (int i = 0; i < 8; ++i) gp0[i * 64] = (int)pd[i];
    }

    __syncthreads();   // forward done everywhere; stores drained here

    // reload dirn bits into LDS (both halves free now; layout identical to
    // the original sdirs32 layout the backward walk expects)
    {
        const float4* g4 = (const float4*)gd32;
        float4* s4 = (float4*)sdirs;
        for (int i = tid; i < TY_ * 16 / 4; i += 576) s4[i] = g4[i];
    }
    __syncthreads();

    int* pb = path + b * TY_;
    for (int j = t_y + tid; j < TY_; j += 576) pb[j] = -1;

    if (tid == 0) {
        int idx = t_x - 1;
        int j   = t_y - 1;
        while (j >= 0) {
            int n  = (j + 1 < 8) ? (j + 1) : 8;
            int bs = (idx - 7) >> 3; if (bs < 0) bs = 0;
            int b2 = bs + 1;         if (b2 > 63) b2 = 63;
            unsigned lo[8], hi[8];
#pragma unroll
            for (int r = 0; r < 8; ++r) {
                if (r < n) {
                    int jr = j - r;
                    int rb = (jr >> 2) * 256 + (jr & 3);
                    lo[r] = sdirs[rb + bs * 4];
                    hi[r] = sdirs[rb + b2 * 4];
                }
            }
#pragma unroll
            for (int r = 0; r < 8; ++r) {
                if (r < n) {
                    pb[j - r] = idx;
                    int Bi = idx >> 3;
                    unsigned byte = (Bi == bs) ? lo[r] : hi[r];
                    idx -= (int)((byte >> (idx & 7)) & 1u);
                }
            }
            j -= n;
        }
    }
}

// ---------------------------------------------------------------------------
// K4a: attn one-hot write (overwrites the neg_cent scratch region).
// ---------------------------------------------------------------------------
__global__ __launch_bounds__(256) void k_attn(const int* __restrict__ path,
                                              float* __restrict__ attn) {
    int i   = blockIdx.x * 256 + threadIdx.x;   // over B*TY*TX/4
    int tx0 = (i & 127) << 2;                   // TX/4 = 128
    int bty = i >> 7;                           // b*TY + ty
    int p   = path[bty];
    float4 o;
    o.x = (p == tx0)     ? 1.f : 0.f;
    o.y = (p == tx0 + 1) ? 1.f : 0.f;
    o.z = (p == tx0 + 2) ? 1.f : 0.f;
    o.w = (p == tx0 + 3) ? 1.f : 0.f;
    ((float4*)attn)[i] = o;
}

// ---------------------------------------------------------------------------
// K4b: m_p_a / logs_p_a gather: out[b,c,ty] = (path[ty]>=0) ? in[b,c,path] : 0
// ---------------------------------------------------------------------------
__global__ __launch_bounds__(256) void k_proj(const int* __restrict__ path,
                                              const float* __restrict__ mp,
                                              const float* __restrict__ logsp,
                                              float* __restrict__ mpa,
                                              float* __restrict__ logsa) {
    int i   = blockIdx.x * 256 + threadIdx.x;   // over B*C*TY/4
    int ty0 = (i & 511) << 2;                   // TY/4 = 512
    int bc  = i >> 9;                           // b*C + c
    int b   = bc / C_;
    const int4 p4 = *(const int4*)(path + b * TY_ + ty0);
    const float* mrow = mp    + (size_t)bc * TX_;
    const float* lrow = logsp + (size_t)bc * TX_;
    float4 mo, lo;
    mo.x = (p4.x >= 0) ? mrow[p4.x] : 0.f;  lo.x = (p4.x >= 0) ? lrow[p4.x] : 0.f;
    mo.y = (p4.y >= 0) ? mrow[p4.y] : 0.f;  lo.y = (p4.y >= 0) ? lrow[p4.y] : 0.f;
    mo.z = (p4.z >= 0) ? mrow[p4.z] : 0.f;  lo.z = (p4.z >= 0) ? lrow[p4.z] : 0.f;
    mo.w = (p4.w >= 0) ? mrow[p4.w] : 0.f;  lo.w = (p4.w >= 0) ? lrow[p4.w] : 0.f;
    ((float4*)mpa)[i]   = mo;
    ((float4*)logsa)[i] = lo;
}

// ---------------------------------------------------------------------------
// K4c: random segment slice of z + ids output (replicates ref f32 math).
// ---------------------------------------------------------------------------
__global__ __launch_bounds__(256) void k_slice(const float* __restrict__ z,
                                               const int* __restrict__ yl,
                                               const float* __restrict__ ru,
                                               float* __restrict__ zs,
                                               float* __restrict__ oid) {
    int b = blockIdx.x;
    int safe = yl[b]; if (safe > TY_) safe = TY_;
    int idsmax = safe - SEG_; if (idsmax < 0) idsmax = 0;
    int ids = (int)(ru[b] * ((float)idsmax + 1e-8f));
    int lim = safe - ids;
    for (int t = threadIdx.x; t < C_ * SEG_; t += 256) {
        int c = t >> 5, k = t & 31;
        zs[b * C_ * SEG_ + t] =
            (k < lim) ? z[((size_t)b * C_ + c) * TY_ + ids + k] : 0.f;
    }
    if (threadIdx.x == 0) oid[b] = (float)ids;
}

// ---------------------------------------------------------------------------
extern "C" void kernel_launch(void* const* d_in, const int* in_sizes, int n_in,
                              void* d_out, int out_size, void* d_ws, size_t ws_size,
                              hipStream_t stream) {
    const float* z     = (const float*)d_in[0];
    const float* zp    = (const float*)d_in[1];
    const float* mp    = (const float*)d_in[2];
    const float* logsp = (const float*)d_in[3];
    const int*   xl    = (const int*)d_in[4];
    const int*   yl    = (const int*)d_in[5];
    const float* ru    = (const float*)d_in[6];

    float* out     = (float*)d_out;
    float* o_zs    = out;                  // 98304
    float* o_ids   = out + 98304;          // 16
    float* o_attn  = out + 98320;          // 16777216 (also neg_cent scratch)
    float* o_mpa   = out + 16875536;       // 6291456
    float* o_logsa = out + 23166992;       // 6291456

    float* Bmat  = (float*)d_ws;                        // 3,145,728 f
    float* cterm = Bmat + (size_t)B_ * K_ * TX_;        // 8192 f
    int*   path  = (int*)(cterm + B_ * TX_);            // 32768 i32
    int*   gdirs = (int*)o_mpa;   // 2 MB dirn scratch; k_proj overwrites later

    // allow 128 KiB dynamic LDS for the fused DP kernel (host-side, not a
    // stream op — safe under graph capture; idempotent, called every launch)
    hipFuncSetAttribute((const void*)k_dp,
                        hipFuncAttributeMaxDynamicSharedMemorySize,
                        TY_ * 64);

    hipLaunchKernelGGL(k_prep, dim3(TX_ / 128, B_), dim3(128), 0, stream,
                       mp, logsp, Bmat, cterm);
    hipLaunchKernelGGL(k_gemm, dim3(TX_ / 128, TY_ / 128, B_), dim3(256), 0, stream,
                       zp, Bmat, cterm, o_attn);
    hipLaunchKernelGGL(k_dp, dim3(B_), dim3(576), TY_ * 64, stream,
                       o_attn, xl, yl, path, gdirs);
    hipLaunchKernelGGL(k_attn, dim3(B_ * TY_ * TX_ / 4 / 256), dim3(256), 0, stream,
                       path, o_attn);
    hipLaunchKernelGGL(k_proj, dim3(B_ * C_ * TY_ / 4 / 256), dim3(256), 0, stream,
                       path, mp, logsp, o_mpa, o_logsa);
    hipLaunchKernelGGL(k_slice, dim3(B_), dim3(256), 0, stream,
                       z, yl, ru, o_zs, o_ids);
}